// Round 4
// baseline (177.706 us; speedup 1.0000x reference)
//
#include <hip/hip_runtime.h>
#include <math.h>

typedef __bf16 bf16x8 __attribute__((ext_vector_type(8)));
typedef float f32x4 __attribute__((ext_vector_type(4)));
typedef float f32x16 __attribute__((ext_vector_type(16)));
typedef unsigned short u16;
typedef u16 u16x8 __attribute__((ext_vector_type(8)));

#define HID 300
#define NH 4
#define DK 75
#define DKP 80
#define BB 8
#define SS 2048
#define BSROWS (BB*SS)
#define C2   0.16658807f            // (1/sqrt(75)) * log2(e)

#define MFMA(a,b,c)   __builtin_amdgcn_mfma_f32_16x16x32_bf16(a,b,c,0,0,0)
#define MFMA32(a,b,c) __builtin_amdgcn_mfma_f32_32x32x16_bf16(a,b,c,0,0,0)

// truncating hi/lo split (~5 VALU); residual ~2^-15 relative
static __device__ __forceinline__ void split2(float x, u16& hb, u16& lb) {
    const unsigned u = __float_as_uint(x);
    hb = (u16)(u >> 16);
    const float r = x - __uint_as_float(u & 0xffff0000u);
    lb = (u16)(__float_as_uint(r) >> 16);
}
// RNE hi + residual lo (hi rel err ~2^-9): attn operand planes.
static __device__ __forceinline__ void split2rne(float x, u16& hb, u16& lb) {
    const unsigned u = __float_as_uint(x);
    const unsigned uh = ((u + 0x7fffu + ((u >> 16) & 1u)) >> 16) << 16;
    hb = (u16)(uh >> 16);
    const float r = x - __uint_as_float(uh);
    lb = (u16)(__float_as_uint(r) >> 16);
}
// pack two f32 -> 2x bf16 (RNE) in one dword; compiler emits v_cvt_pk_bf16_f32
static __device__ __forceinline__ unsigned pkbf(float a, float b) {
    const unsigned short ua = __builtin_bit_cast(unsigned short, (__bf16)a);
    const unsigned short ub = __builtin_bit_cast(unsigned short, (__bf16)b);
    return (unsigned)ua | ((unsigned)ub << 16);
}

// ---------------------------------------------------------------------------
// prep_w3 (unchanged)
// ---------------------------------------------------------------------------
__global__ __launch_bounds__(256)
void prep_w3(const float* __restrict__ Wq, const float* __restrict__ Wk,
             const float* __restrict__ Wv,
             u16* __restrict__ wph, u16* __restrict__ wpl)
{
    const int idx = blockIdx.x * 256 + threadIdx.x;   // 3*4*80*40 = 38400
    if (idx >= 38400) return;
    const int c8 = idx % 40;
    int r = idx / 40;
    const int n = r % 80; r /= 80;
    const int h = r & 3;  r >>= 2;
    const int mat = r;                                 // 0..2
    const float* W = (mat == 0) ? Wq : (mat == 1) ? Wk : Wv;
    const int col0 = c8 * 8;
    float v[8];
#pragma unroll
    for (int j = 0; j < 8; ++j) v[j] = 0.f;
    if (n < DK) {
        const float* s = W + (size_t)(h * DK + n) * HID + col0;
        if (col0 + 8 <= HID) {
#pragma unroll
            for (int j = 0; j < 8; ++j) v[j] = s[j];
        } else {
#pragma unroll
            for (int j = 0; j < 8; ++j) v[j] = (col0 + j < HID) ? s[j] : 0.f;
        }
    }
    u16x8 hv, lv;
#pragma unroll
    for (int j = 0; j < 8; ++j) {
        u16 hb, lb;
        split2(v[j], hb, lb);
        hv[j] = hb; lv[j] = lb;
    }
    const size_t base = ((size_t)((mat * 4 + h) * 80 + n)) * 320 + col0;
    *(u16x8*)(wph + base) = hv;
    *(u16x8*)(wpl + base) = lv;
}

// ---------------------------------------------------------------------------
// Shared GEMM body, templated on MODE and heads-per-block HPB.
// Round delta: K-chunk 32 -> 64 (5 staging steps instead of 10): halves the
// barrier/latency events per block; FP-identical accumulation order.
// patch: 1 (Q): col75 hi=1.0 (bias carrier); 2 (K): col75 = mask?0:-160.
// ---------------------------------------------------------------------------
template <int MODE, int HPB>
static __device__ __forceinline__ void gemm_body(
    char* smem, const float* __restrict__ A, const float* __restrict__ W,
    const u16* __restrict__ Wph, const u16* __restrict__ Wpl,
    const float* __restrict__ bias, u16* __restrict__ hiP, u16* __restrict__ loP,
    float* __restrict__ foutP, const int bx, const int hp,
    const int* __restrict__ pmask, const float scale, const int patch)
{
    constexpr int WROWS = 80 * HPB;
    constexpr int NT = 5 * HPB;
    constexpr int KC = 64;                 // bf16 cols per plane per step
    u16* Ah = (u16*)smem;                  // [128][64]
    u16* Al = Ah + 128 * KC;
    u16* Wh = Al + 128 * KC;               // [WROWS][64]
    u16* Wl = Wh + WROWS * KC;

    const int t = threadIdx.x;
    const int wv = t >> 6, l = t & 63, qc = l & 15, g = l >> 4;
    const int row0 = bx * 128;
    const int b = row0 >> 11;
    const int s0 = row0 & 2047;

    const f32x4 zf = {0.f, 0.f, 0.f, 0.f};
    f32x4 acc[2][NT];
#pragma unroll
    for (int mt = 0; mt < 2; ++mt)
#pragma unroll
        for (int nt = 0; nt < NT; ++nt) acc[mt][nt] = zf;

    // ---- prefetch state ----
    const int rA = t >> 1, halfA = t & 1;
    float4 aPf[8];                                    // A tile slice (always)
    constexpr int WJ  = (WROWS * 8 + 255) / 256;      // W copy path (MODE <= 1)
    constexpr int WJ2 = (WROWS * 16 + 255) / 256;     // W convert path (MODE == 2)
    u16x8 wPfH[WJ], wPfL[WJ];
    float4 wPf2[WJ2];

    auto loadA = [&](int step) {
        const int k0 = step * KC + halfA * 32;
        const float* src = A + (size_t)(row0 + rA) * HID + k0;
#pragma unroll
        for (int c4 = 0; c4 < 8; ++c4) {
            const int k = k0 + c4 * 4;
            float4 v;
            if (k + 4 <= HID) v = *(const float4*)(src + c4 * 4);
            else {
                v.x = (k + 0 < HID) ? src[c4 * 4 + 0] : 0.f;
                v.y = (k + 1 < HID) ? src[c4 * 4 + 1] : 0.f;
                v.z = (k + 2 < HID) ? src[c4 * 4 + 2] : 0.f;
                v.w = (k + 3 < HID) ? src[c4 * 4 + 3] : 0.f;
            }
            aPf[c4] = v;
        }
    };
    auto loadW = [&](int step) {
        const int k0 = step * KC;
        if constexpr (MODE <= 1) {
#pragma unroll
            for (int j = 0; j < WJ; ++j) {
                const int idx = j * 256 + t;
                if (idx < WROWS * 8) {
                    const int n = idx >> 3, c = idx & 7;
                    const int nh = (n >= 80) ? 1 : 0, nn = n - nh * 80;
                    const size_t wo = (size_t)((hp * HPB + nh) * 80 + nn) * 320 + k0 + c * 8;
                    wPfH[j] = *(const u16x8*)(Wph + wo);
                    wPfL[j] = *(const u16x8*)(Wpl + wo);
                }
            }
        } else {
#pragma unroll
            for (int j = 0; j < WJ2; ++j) {
                const int idx = j * 256 + t;
                if (idx < WROWS * 16) {
                    const int n = idx >> 4, c = idx & 15;
                    const int nh = (n >= 80) ? 1 : 0, nn = n - nh * 80;
                    const int k = k0 + c * 4;
                    float4 v = make_float4(0.f, 0.f, 0.f, 0.f);
                    if (nn < DK) {
                        const float* src = W + (size_t)((hp * HPB + nh) * DK + nn) * HID + k;
                        if (k + 4 <= HID) v = *(const float4*)src;
                        else {
                            v.x = (k + 0 < HID) ? src[0] : 0.f;
                            v.y = (k + 1 < HID) ? src[1] : 0.f;
                            v.z = (k + 2 < HID) ? src[2] : 0.f;
                            v.w = (k + 3 < HID) ? src[3] : 0.f;
                        }
                    }
                    wPf2[j] = v;
                }
            }
        }
    };
    auto writeA = [&]() {
        u16* dh = Ah + rA * KC + halfA * 32;
        u16* dl = Al + rA * KC + halfA * 32;
#pragma unroll
        for (int c4 = 0; c4 < 8; ++c4) {
            ushort4 h4, l4;
            split2(aPf[c4].x, h4.x, l4.x);
            split2(aPf[c4].y, h4.y, l4.y);
            split2(aPf[c4].z, h4.z, l4.z);
            split2(aPf[c4].w, h4.w, l4.w);
            *(ushort4*)(dh + c4 * 4) = h4;
            *(ushort4*)(dl + c4 * 4) = l4;
        }
    };
    auto writeW = [&]() {
        if constexpr (MODE <= 1) {
#pragma unroll
            for (int j = 0; j < WJ; ++j) {
                const int idx = j * 256 + t;
                if (idx < WROWS * 8) {
                    const int n = idx >> 3, c = idx & 7;
                    *(u16x8*)(Wh + n * KC + c * 8) = wPfH[j];
                    *(u16x8*)(Wl + n * KC + c * 8) = wPfL[j];
                }
            }
        } else {
#pragma unroll
            for (int j = 0; j < WJ2; ++j) {
                const int idx = j * 256 + t;
                if (idx < WROWS * 16) {
                    const int n = idx >> 4, c = idx & 15;
                    ushort4 h4, l4;
                    split2(wPf2[j].x, h4.x, l4.x);
                    split2(wPf2[j].y, h4.y, l4.y);
                    split2(wPf2[j].z, h4.z, l4.z);
                    split2(wPf2[j].w, h4.w, l4.w);
                    *(ushort4*)(Wh + n * KC + c * 4) = h4;
                    *(ushort4*)(Wl + n * KC + c * 4) = l4;
                }
            }
        }
    };

    loadA(0);
    loadW(0);

    for (int step = 0; step < 5; ++step) {
        __syncthreads();          // previous step's MFMA reads complete
        writeA();                 // regs -> LDS (vmcnt wait here)
        writeW();
        __syncthreads();          // writes visible
        if (step < 4) {           // issue next tile NOW; hides under MFMA
            loadA(step + 1);
            loadW(step + 1);
        }
        // ---- compute: one K=64 chunk as two K=32 sub-chunks ----
#pragma unroll
        for (int cc = 0; cc < 2; ++cc) {
            bf16x8 ah[2], al2[2];
#pragma unroll
            for (int mt = 0; mt < 2; ++mt) {
                const int roff = (wv * 32 + mt * 16 + qc) * KC + cc * 32 + g * 8;
                ah[mt]  = *(const bf16x8*)(Ah + roff);
                al2[mt] = *(const bf16x8*)(Al + roff);
            }
#pragma unroll
            for (int nt = 0; nt < NT; ++nt) {
                const int woff = (nt * 16 + qc) * KC + cc * 32 + g * 8;
                const bf16x8 bh = *(const bf16x8*)(Wh + woff);
                const bf16x8 bl = *(const bf16x8*)(Wl + woff);
#pragma unroll
                for (int mt = 0; mt < 2; ++mt) {
                    acc[mt][nt] = MFMA(ah[mt],  bh, acc[mt][nt]);
                    acc[mt][nt] = MFMA(al2[mt], bh, acc[mt][nt]);
                    acc[mt][nt] = MFMA(ah[mt],  bl, acc[mt][nt]);
                }
            }
        }
    }
    __syncthreads();

    // ---- epilogue via LDS: HPB per-head passes ----
#pragma unroll
    for (int ph = 0; ph < HPB; ++ph) {
        const int h = hp * HPB + ph;
        if constexpr (MODE <= 1) {
            unsigned* epi = (unsigned*)smem;   // [128][84] packed hi|lo<<16
#pragma unroll
            for (int mt = 0; mt < 2; ++mt)
#pragma unroll
                for (int nt = 0; nt < 5; ++nt)
#pragma unroll
                    for (int r = 0; r < 4; ++r) {
                        u16 hb, lb;
                        split2rne(acc[mt][ph * 5 + nt][r] * scale, hb, lb);  // RNE hi
                        if (patch != 0 && nt == 4 && qc == 11) {             // col d=75
                            if (patch == 1) { hb = (u16)0x3F80; lb = 0; }    // 1.0
                            else {
                                const int sr = s0 + wv * 32 + mt * 16 + g * 4 + r;
                                hb = (pmask[b * SS + sr] != 0) ? (u16)0 : (u16)0xC320; // -160
                                lb = 0;
                            }
                        }
                        epi[(wv * 32 + mt * 16 + g * 4 + r) * 84 + nt * 16 + qc] =
                            (unsigned)hb | ((unsigned)lb << 16);
                    }
            __syncthreads();
            if constexpr (MODE == 0) {
                const int r = t >> 1, half = t & 1;
                const unsigned* row = epi + r * 84 + half * 40;
                const size_t base = ((size_t)(b * NH + h) * SS + s0 + r) * DKP + half * 40;
                u16* dh = hiP + base;
#pragma unroll
                for (int i = 0; i < 5; ++i) {
                    u16x8 hv, lv;
#pragma unroll
                    for (int j = 0; j < 8; ++j) {
                        const unsigned u = row[i * 8 + j];
                        hv[j] = (u16)u; lv[j] = (u16)(u >> 16);
                    }
                    *(u16x8*)(dh + i * 8) = hv;
                    if (loP) *(u16x8*)(loP + base + i * 8) = lv;
                }
            } else {
#pragma unroll
                for (int i = 0; i < 3; ++i) {
                    const int idx = i * 256 + t;
                    if (idx < 640) {
                        const int d = idx >> 3, sc = (idx & 7) * 16;
                        const size_t base = ((size_t)(b * NH + h) * DKP + d) * SS + s0 + sc;
                        u16* dh = hiP + base;
                        u16x8 h0, h1, l0, l1;
#pragma unroll
                        for (int j = 0; j < 8; ++j) {
                            unsigned u = epi[(sc + j) * 84 + d];
                            h0[j] = (u16)u; l0[j] = (u16)(u >> 16);
                            u = epi[(sc + 8 + j) * 84 + d];
                            h1[j] = (u16)u; l1[j] = (u16)(u >> 16);
                        }
                        *(u16x8*)dh = h0; *(u16x8*)(dh + 8) = h1;
                        if (loP) {
                            *(u16x8*)(loP + base) = l0;
                            *(u16x8*)(loP + base + 8) = l1;
                        }
                    }
                }
            }
        } else {
            float* epf = (float*)smem;         // [128][84] fp32
#pragma unroll
            for (int mt = 0; mt < 2; ++mt)
#pragma unroll
                for (int nt = 0; nt < 5; ++nt)
#pragma unroll
                    for (int r = 0; r < 4; ++r)
                        epf[(wv * 32 + mt * 16 + g * 4 + r) * 84 + nt * 16 + qc] =
                            acc[mt][ph * 5 + nt][r];
            __syncthreads();
            for (int i = 0; i < 38; ++i) {
                const int idx = i * 256 + t;
                if (idx < 128 * DK) {
                    const int r = idx / DK, c = idx - r * DK;
                    foutP[(size_t)(row0 + r) * HID + h * DK + c] = epf[r * 84 + c] + bias[h * DK + c];
                }
            }
        }
        if (ph + 1 < HPB) __syncthreads();   // epi buffer reuse by next pass
    }
}

__global__ __launch_bounds__(256, 2)
void proj3_gemm(const float* __restrict__ Aq, const float* __restrict__ Ak,
                const float* __restrict__ Av, const int* __restrict__ mask,
                const u16* __restrict__ wph, const u16* __restrict__ wpl,
                u16* __restrict__ qh, u16* __restrict__ ql,
                u16* __restrict__ kh, u16* __restrict__ vh)
{
    __shared__ char smem[73728];   // staging (128+160)*64*2*2 = 73728 > epi 43008
    const int z = blockIdx.z;
    const float* A = (z == 0) ? Aq : (z == 1) ? Ak : Av;
    const size_t WMAT = (size_t)4 * 80 * 320;
    u16* hiP = (z == 0) ? qh : (z == 1) ? kh : vh;
    u16* loP = (z == 0) ? ql : nullptr;
    const float scale = (z == 0) ? C2 : 1.0f;          // fold score scale into Q
    const int patch = (z == 0) ? 1 : (z == 1) ? 2 : 0; // bias column d=75
    if (z == 2)
        gemm_body<1, 2>(smem, A, nullptr, wph + z * WMAT, wpl + z * WMAT,
                        nullptr, hiP, loP, nullptr, blockIdx.x, blockIdx.y,
                        mask, scale, patch);
    else
        gemm_body<0, 2>(smem, A, nullptr, wph + z * WMAT, wpl + z * WMAT,
                        nullptr, hiP, loP, nullptr, blockIdx.x, blockIdx.y,
                        mask, scale, patch);
}

__global__ __launch_bounds__(256, 2)
void out_gemm(const float* __restrict__ A, const float* __restrict__ W,
              const float* __restrict__ bias, float* __restrict__ out)
{
    __shared__ char smem[53248];   // (128+80)*64*2*2 = 53248 > epi 43008
    gemm_body<2, 1>(smem, A, W, nullptr, nullptr, bias, nullptr, nullptr, out,
                    blockIdx.x, blockIdx.y, nullptr, 1.0f, 0);
}

// ---------------------------------------------------------------------------
// Flash attention. Round delta vs round-2 proven (91 us isolated):
//   - K swizzle widened (q&7 -> q&15, bijective in the 256B row): K-read
//     ds_read_b128 4-way conflicts -> free 2-way. pswz stays (q&7).
//   - 3-deep global prefetch (two register sets, parity-static selection):
//     loads in flight ~2 iterations (~1200cy) > HBM latency.
// ---------------------------------------------------------------------------
__global__ __launch_bounds__(256, 2)
void attn_mfma32(const u16* __restrict__ qhi, const u16* __restrict__ qlo,
                 const u16* __restrict__ khi, const u16* __restrict__ vhi,
                 const int* __restrict__ mask, float* __restrict__ xout)
{
    __shared__ u16 KsH[2 * 8192];   // [buf][seq 64][256B rows, swizzled]
    __shared__ u16 VsH[2 * 6144];   // [buf][d 96 (80..95 zero)][128B rows]
    __shared__ u16 Ps[4 * 2048];    // per-wave [q 32][seq 64 = 128B rows]

    const int t = threadIdx.x;
    const int wv = t >> 6;
    const int l = t & 63;
    const int q = l & 31;
    const int hi = l >> 5;

    const int bx = blockIdx.x;
    const int xcd = bx & 7, idx = bx >> 3;
    const int bh = xcd * 4 + (idx & 3);
    const int qt = idx >> 2;
    const int b = bh >> 2;
    const int h = bh & 3;
    const int q0 = qt * 128;

    {
        const int rr = (t >> 4) & 15, o8 = t & 15;
        *(uint2*)(VsH + (80 + rr) * 64 + o8 * 4) = make_uint2(0u, 0u);
        *(uint2*)(VsH + 6144 + (80 + rr) * 64 + o8 * 4) = make_uint2(0u, 0u);
    }

    const size_t planeQK = (size_t)bh * (SS * DKP);
    const int qrow = q0 + wv * 32 + q;
    const int mq = (mask[b * SS + qrow] != 0);
    const u16x8 qm = (u16x8)(u16)(mq ? 0xFFFFu : 0u);  // !mq -> Q=0 -> P uniform

    bf16x8 Qh[5], Ql[5];
    {
        const u16* ph = qhi + planeQK + (size_t)qrow * DKP;
        const u16* pl = qlo + planeQK + (size_t)qrow * DKP;
#pragma unroll
        for (int ch = 0; ch < 5; ++ch) {
            u16x8 ua = *(const u16x8*)(ph + 16 * ch + 8 * hi) & qm;
            u16x8 ub = *(const u16x8*)(pl + 16 * ch + 8 * hi) & qm;
            Qh[ch] = *(bf16x8*)&ua;
            Ql[ch] = *(bf16x8*)&ub;
        }
    }

    const u16* kH = khi + planeQK;
    const u16* vH = vhi + (size_t)bh * (DKP * SS);
    u16* PsW = Ps + wv * 2048;

    int kOff[5], kLds[5], vOff[5], vLds[5];
#pragma unroll
    for (int i = 0; i < 5; ++i) {
        const int gi = t + i * 256;
        const int r = gi / 20, c8 = gi % 20;
        kOff[i] = r * 160 + c8 * 8;
        kLds[i] = r * 256 + ((c8 * 8) ^ ((r & 15) << 4));   // widened swizzle
        const int d = gi >> 4, cv = gi & 15;
        vOff[i] = d * 4096 + cv * 8;
        vLds[i] = d * 128 + ((cv * 8) ^ ((d & 7) << 4));
    }

    uint2 krA[5], vrA[5], krB[5], vrB[5];
#define LOADT(KT, KR, VR) do { _Pragma("unroll") \
    for (int i = 0; i < 5; ++i) { \
        KR[i] = *(const uint2*)((const char*)kH + (size_t)(KT) * 10240 + kOff[i]); \
        VR[i] = *(const uint2*)((const char*)vH + (size_t)(KT) * 128 + vOff[i]); \
    } } while (0)
#define WRITET(BUF, KR, VR) do { _Pragma("unroll") \
    for (int i = 0; i < 5; ++i) { \
        *(uint2*)((char*)(KsH + (BUF) * 8192) + kLds[i]) = KR[i]; \
        *(uint2*)((char*)(VsH + (BUF) * 6144) + vLds[i]) = VR[i]; \
    } } while (0)

    LOADT(0, krA, vrA);
    WRITET(0, krA, vrA);
    LOADT(1, krA, vrA);    // A holds kt=1 (consumed at end of kt=0)
    LOADT(2, krB, vrB);    // B holds kt=2 (consumed at end of kt=1)
    __syncthreads();

    f32x16 O[3];
#pragma unroll
    for (int dt = 0; dt < 3; ++dt) O[dt] = (f32x16){};
    float ll = 0.f;
    const int kswz = (q & 15) << 4;        // K-read swizzle (widened)
    const int pswz = (q & 7) << 4;         // Ps swizzle (128B rows)

    for (int kt = 0; kt < 32; ++kt) {
        const int cur = kt & 1;
        const char* Kc = (const char*)(KsH + cur * 8192);
        const char* Vc = (const char*)(VsH + cur * 6144);

        f32x16 s0 = (f32x16){}, s1 = (f32x16){};
#pragma unroll
        for (int ch = 0; ch < 5; ++ch) {
            const int o0 = (32 * ch + 16 * hi) ^ kswz;
            const int o1 = (32 * ch + 16 * hi) ^ (((32 + q) & 15) << 4);
            const bf16x8 a0 = *(const bf16x8*)(Kc + q * 256 + o0);
            const bf16x8 a1 = *(const bf16x8*)(Kc + (32 + q) * 256 + o1);
            s0 = MFMA32(a0, Qh[ch], s0);
            s0 = MFMA32(a0, Ql[ch], s0);
            s1 = MFMA32(a1, Qh[ch], s1);
            s1 = MFMA32(a1, Ql[ch], s1);
        }

        // ---- softmax numerators: e = exp2(s) directly (scale/mask folded) ----
        float p0 = 0.f, p1 = 0.f, p2 = 0.f, p3 = 0.f;
#pragma unroll
        for (int sb = 0; sb < 2; ++sb) {
            const f32x16 sv = sb ? s1 : s0;
            float e[16];
#pragma unroll
            for (int r = 0; r < 16; r += 4) {
                e[r + 0] = __builtin_amdgcn_exp2f(sv[r + 0]);
                e[r + 1] = __builtin_amdgcn_exp2f(sv[r + 1]);
                e[r + 2] = __builtin_amdgcn_exp2f(sv[r + 2]);
                e[r + 3] = __builtin_amdgcn_exp2f(sv[r + 3]);
                p0 += e[r + 0]; p1 += e[r + 1]; p2 += e[r + 2]; p3 += e[r + 3];
            }
#pragma unroll
            for (int rr = 0; rr < 4; ++rr) {
                uint2 w;
                w.x = pkbf(e[4 * rr + 0], e[4 * rr + 1]);
                w.y = pkbf(e[4 * rr + 2], e[4 * rr + 3]);
                const int o = (sb * 64 + 16 * rr + 8 * hi) ^ pswz;
                *(uint2*)((char*)PsW + q * 128 + o) = w;
            }
        }
        ll += (p0 + p1) + (p2 + p3);

        // ---- PV ----
#pragma unroll
        for (int c = 0; c < 4; ++c) {
            const int po = q * 128 + ((32 * c + 16 * hi) ^ pswz);
            const bf16x8 pA = *(const bf16x8*)((char*)PsW + po);
#pragma unroll
            for (int dt = 0; dt < 3; ++dt) {
                const int drow = 32 * dt + q;
                const int vb = drow * 128 + ((32 * c + 16 * hi) ^ ((drow & 7) << 4));
                const bf16x8 vh8 = *(const bf16x8*)(Vc + vb);
                O[dt] = MFMA32(vh8, pA, O[dt]);
            }
        }

        if (kt < 31) {
            if ((kt & 1) == 0) {
                WRITET(cur ^ 1, krA, vrA);
                if (kt < 29) LOADT(kt + 3, krA, vrA);
            } else {
                WRITET(cur ^ 1, krB, vrB);
                if (kt < 29) LOADT(kt + 3, krB, vrB);
            }
        }
        __syncthreads();
    }
#undef LOADT
#undef WRITET

    ll += __shfl_xor(ll, 32);
    {
        const float inv = 1.0f / ll;
        float* o = xout + (size_t)(b * SS + qrow) * HID + h * DK;
#pragma unroll
        for (int dt = 0; dt < 3; ++dt)
#pragma unroll
            for (int r = 0; r < 16; ++r) {
                const int d = 32 * dt + (r & 3) + 8 * (r >> 2) + 4 * hi;
                if (d < DK) o[d] = O[dt][r] * inv;
            }
    }
}

// ---------------------------------------------------------------------------
extern "C" void kernel_launch(void* const* d_in, const int* in_sizes, int n_in,
                              void* d_out, int out_size, void* d_ws, size_t ws_size,
                              hipStream_t stream)
{
    const float* query = (const float*)d_in[0];
    const float* key_t = (const float*)d_in[1];
    const float* value = (const float*)d_in[2];
    const int*   mask  = (const int*)d_in[3];
    const float* Wq    = (const float*)d_in[4];
    const float* Wk    = (const float*)d_in[5];
    const float* Wv    = (const float*)d_in[6];
    const float* Wo    = (const float*)d_in[7];
    const float* bo    = (const float*)d_in[8];
    float* out = (float*)d_out;

    // Proven workspace layout (<=82.58 MB). kl/vl slots retained but unused.
    const size_t PL = (size_t)BB * NH * SS * DKP;
    u16* qh = (u16*)d_ws;
    u16* ql = qh + PL;
    u16* kh = ql + PL;
    u16* kl = kh + PL;   (void)kl;
    u16* vh = kl + PL;
    u16* vl = vh + PL;
    float* xws = (float*)(vl + PL);
    u16* wph = (u16*)xws;                         // [3][4][80][320] hi
    u16* wpl = wph + (size_t)3 * 4 * 80 * 320;    // lo (1.23 MB total)

    const dim3 blk(256, 1, 1);

    prep_w3<<<150, blk, 0, stream>>>(Wq, Wk, Wv, wph, wpl);

    proj3_gemm<<<dim3(128, 2, 3), blk, 0, stream>>>(query, key_t, value, mask,
                                                    wph, wpl,
                                                    qh, ql, kh, vh);

    attn_mfma32<<<dim3(512, 1, 1), blk, 0, stream>>>(qh, ql, kh, vh, mask, xws);

    out_gemm<<<dim3(128, NH, 1), blk, 0, stream>>>(xws, Wo, bo, out);
}

// Round 5
// 171.871 us; speedup vs baseline: 1.0339x; 1.0339x over previous
//
#include <hip/hip_runtime.h>
#include <math.h>

typedef __bf16 bf16x8 __attribute__((ext_vector_type(8)));
typedef float f32x4 __attribute__((ext_vector_type(4)));
typedef float f32x16 __attribute__((ext_vector_type(16)));
typedef unsigned short u16;
typedef u16 u16x8 __attribute__((ext_vector_type(8)));

#define HID 300
#define NH 4
#define DK 75
#define DKP 80
#define BB 8
#define SS 2048
#define BSROWS (BB*SS)
#define C2   0.16658807f            // (1/sqrt(75)) * log2(e)

#define MFMA(a,b,c)   __builtin_amdgcn_mfma_f32_16x16x32_bf16(a,b,c,0,0,0)
#define MFMA32(a,b,c) __builtin_amdgcn_mfma_f32_32x32x16_bf16(a,b,c,0,0,0)

// truncating hi/lo split (~5 VALU); residual ~2^-15 relative
static __device__ __forceinline__ void split2(float x, u16& hb, u16& lb) {
    const unsigned u = __float_as_uint(x);
    hb = (u16)(u >> 16);
    const float r = x - __uint_as_float(u & 0xffff0000u);
    lb = (u16)(__float_as_uint(r) >> 16);
}
// RNE hi + residual lo (hi rel err ~2^-9): attn operand planes.
static __device__ __forceinline__ void split2rne(float x, u16& hb, u16& lb) {
    const unsigned u = __float_as_uint(x);
    const unsigned uh = ((u + 0x7fffu + ((u >> 16) & 1u)) >> 16) << 16;
    hb = (u16)(uh >> 16);
    const float r = x - __uint_as_float(uh);
    lb = (u16)(__float_as_uint(r) >> 16);
}
// pack two f32 -> 2x bf16 (RNE) in one dword; compiler emits v_cvt_pk_bf16_f32
static __device__ __forceinline__ unsigned pkbf(float a, float b) {
    const unsigned short ua = __builtin_bit_cast(unsigned short, (__bf16)a);
    const unsigned short ub = __builtin_bit_cast(unsigned short, (__bf16)b);
    return (unsigned)ua | ((unsigned)ub << 16);
}

// ---------------------------------------------------------------------------
// prep_w3 (unchanged)
// ---------------------------------------------------------------------------
__global__ __launch_bounds__(256)
void prep_w3(const float* __restrict__ Wq, const float* __restrict__ Wk,
             const float* __restrict__ Wv,
             u16* __restrict__ wph, u16* __restrict__ wpl)
{
    const int idx = blockIdx.x * 256 + threadIdx.x;   // 3*4*80*40 = 38400
    if (idx >= 38400) return;
    const int c8 = idx % 40;
    int r = idx / 40;
    const int n = r % 80; r /= 80;
    const int h = r & 3;  r >>= 2;
    const int mat = r;                                 // 0..2
    const float* W = (mat == 0) ? Wq : (mat == 1) ? Wk : Wv;
    const int col0 = c8 * 8;
    float v[8];
#pragma unroll
    for (int j = 0; j < 8; ++j) v[j] = 0.f;
    if (n < DK) {
        const float* s = W + (size_t)(h * DK + n) * HID + col0;
        if (col0 + 8 <= HID) {
#pragma unroll
            for (int j = 0; j < 8; ++j) v[j] = s[j];
        } else {
#pragma unroll
            for (int j = 0; j < 8; ++j) v[j] = (col0 + j < HID) ? s[j] : 0.f;
        }
    }
    u16x8 hv, lv;
#pragma unroll
    for (int j = 0; j < 8; ++j) {
        u16 hb, lb;
        split2(v[j], hb, lb);
        hv[j] = hb; lv[j] = lb;
    }
    const size_t base = ((size_t)((mat * 4 + h) * 80 + n)) * 320 + col0;
    *(u16x8*)(wph + base) = hv;
    *(u16x8*)(wpl + base) = lv;
}

// ---------------------------------------------------------------------------
// Shared GEMM body (round-3 proven: KC=32, 80B rows conflict-free, HPB merge).
// patch: 1 (Q): col75 hi=1.0 (bias carrier); 2 (K): col75 = mask?0:-160.
// ---------------------------------------------------------------------------
template <int MODE, int HPB>
static __device__ __forceinline__ void gemm_body(
    char* smem, const float* __restrict__ A, const float* __restrict__ W,
    const u16* __restrict__ Wph, const u16* __restrict__ Wpl,
    const float* __restrict__ bias, u16* __restrict__ hiP, u16* __restrict__ loP,
    float* __restrict__ foutP, const int bx, const int hp,
    const int* __restrict__ pmask, const float scale, const int patch)
{
    constexpr int WROWS = 80 * HPB;
    constexpr int NT = 5 * HPB;
    u16* Ah = (u16*)smem;              // [128][40]
    u16* Al = Ah + 128 * 40;
    u16* Wh = Al + 128 * 40;           // [WROWS][40]
    u16* Wl = Wh + WROWS * 40;

    const int t = threadIdx.x;
    const int wv = t >> 6, l = t & 63, qc = l & 15, g = l >> 4;
    const int row0 = bx * 128;
    const int b = row0 >> 11;
    const int s0 = row0 & 2047;

    const f32x4 zf = {0.f, 0.f, 0.f, 0.f};
    f32x4 acc[2][NT];
#pragma unroll
    for (int mt = 0; mt < 2; ++mt)
#pragma unroll
        for (int nt = 0; nt < NT; ++nt) acc[mt][nt] = zf;

    // ---- prefetch state ----
    const int rA = t >> 1, halfA = t & 1;
    float4 aPf[4];                                    // A tile slice (always)
    constexpr int WJ  = (WROWS * 4 + 255) / 256;      // W copy path (MODE <= 1)
    constexpr int WJ2 = (WROWS * 8 + 255) / 256;      // W convert path (MODE == 2)
    u16x8 wPfH[WJ], wPfL[WJ];
    float4 wPf2[WJ2];

    auto loadA = [&](int step) {
        const int k0 = step * 32 + halfA * 16;
        const float* src = A + (size_t)(row0 + rA) * HID + k0;
#pragma unroll
        for (int c4 = 0; c4 < 4; ++c4) {
            const int k = k0 + c4 * 4;
            float4 v;
            if (k + 4 <= HID) v = *(const float4*)(src + c4 * 4);
            else {
                v.x = (k + 0 < HID) ? src[c4 * 4 + 0] : 0.f;
                v.y = (k + 1 < HID) ? src[c4 * 4 + 1] : 0.f;
                v.z = (k + 2 < HID) ? src[c4 * 4 + 2] : 0.f;
                v.w = (k + 3 < HID) ? src[c4 * 4 + 3] : 0.f;
            }
            aPf[c4] = v;
        }
    };
    auto loadW = [&](int step) {
        const int k0 = step * 32;
        if constexpr (MODE <= 1) {
#pragma unroll
            for (int j = 0; j < WJ; ++j) {
                const int idx = j * 256 + t;
                if (idx < WROWS * 4) {
                    const int n = idx >> 2, c = idx & 3;
                    const int nh = (n >= 80) ? 1 : 0, nn = n - nh * 80;
                    const size_t wo = (size_t)((hp * HPB + nh) * 80 + nn) * 320 + k0 + c * 8;
                    wPfH[j] = *(const u16x8*)(Wph + wo);
                    wPfL[j] = *(const u16x8*)(Wpl + wo);
                }
            }
        } else {
#pragma unroll
            for (int j = 0; j < WJ2; ++j) {
                const int idx = j * 256 + t;
                if (idx < WROWS * 8) {
                    const int n = idx >> 3, c = idx & 7;
                    const int nh = (n >= 80) ? 1 : 0, nn = n - nh * 80;
                    const int k = k0 + c * 4;
                    float4 v = make_float4(0.f, 0.f, 0.f, 0.f);
                    if (nn < DK) {
                        const float* src = W + (size_t)((hp * HPB + nh) * DK + nn) * HID + k;
                        if (k + 4 <= HID) v = *(const float4*)src;
                        else {
                            v.x = (k + 0 < HID) ? src[0] : 0.f;
                            v.y = (k + 1 < HID) ? src[1] : 0.f;
                            v.z = (k + 2 < HID) ? src[2] : 0.f;
                            v.w = (k + 3 < HID) ? src[3] : 0.f;
                        }
                    }
                    wPf2[j] = v;
                }
            }
        }
    };
    auto writeA = [&]() {
        u16* dh = Ah + rA * 40 + halfA * 16;
        u16* dl = Al + rA * 40 + halfA * 16;
#pragma unroll
        for (int c4 = 0; c4 < 4; ++c4) {
            ushort4 h4, l4;
            split2(aPf[c4].x, h4.x, l4.x);
            split2(aPf[c4].y, h4.y, l4.y);
            split2(aPf[c4].z, h4.z, l4.z);
            split2(aPf[c4].w, h4.w, l4.w);
            *(ushort4*)(dh + c4 * 4) = h4;
            *(ushort4*)(dl + c4 * 4) = l4;
        }
    };
    auto writeW = [&]() {
        if constexpr (MODE <= 1) {
#pragma unroll
            for (int j = 0; j < WJ; ++j) {
                const int idx = j * 256 + t;
                if (idx < WROWS * 4) {
                    const int n = idx >> 2, c = idx & 3;
                    *(u16x8*)(Wh + n * 40 + c * 8) = wPfH[j];
                    *(u16x8*)(Wl + n * 40 + c * 8) = wPfL[j];
                }
            }
        } else {
#pragma unroll
            for (int j = 0; j < WJ2; ++j) {
                const int idx = j * 256 + t;
                if (idx < WROWS * 8) {
                    const int n = idx >> 3, c = idx & 7;
                    ushort4 h4, l4;
                    split2(wPf2[j].x, h4.x, l4.x);
                    split2(wPf2[j].y, h4.y, l4.y);
                    split2(wPf2[j].z, h4.z, l4.z);
                    split2(wPf2[j].w, h4.w, l4.w);
                    *(ushort4*)(Wh + n * 40 + c * 4) = h4;
                    *(ushort4*)(Wl + n * 40 + c * 4) = l4;
                }
            }
        }
    };

    loadA(0);
    loadW(0);

    for (int step = 0; step < 10; ++step) {
        __syncthreads();          // previous step's MFMA reads complete
        writeA();                 // regs -> LDS (vmcnt wait here)
        writeW();
        __syncthreads();          // writes visible
        if (step < 9) {           // issue next tile NOW; hides under MFMA
            loadA(step + 1);
            loadW(step + 1);
        }
        // ---- compute: one K=32 chunk ----
        bf16x8 ah[2], al2[2];
#pragma unroll
        for (int mt = 0; mt < 2; ++mt) {
            const int roff = (wv * 32 + mt * 16 + qc) * 40 + g * 8;
            ah[mt]  = *(const bf16x8*)(Ah + roff);
            al2[mt] = *(const bf16x8*)(Al + roff);
        }
#pragma unroll
        for (int nt = 0; nt < NT; ++nt) {
            const int woff = (nt * 16 + qc) * 40 + g * 8;
            const bf16x8 bh = *(const bf16x8*)(Wh + woff);
            const bf16x8 bl = *(const bf16x8*)(Wl + woff);
#pragma unroll
            for (int mt = 0; mt < 2; ++mt) {
                acc[mt][nt] = MFMA(ah[mt],  bh, acc[mt][nt]);
                acc[mt][nt] = MFMA(al2[mt], bh, acc[mt][nt]);
                acc[mt][nt] = MFMA(ah[mt],  bl, acc[mt][nt]);
            }
        }
    }
    __syncthreads();

    // ---- epilogue via LDS: HPB per-head passes ----
#pragma unroll
    for (int ph = 0; ph < HPB; ++ph) {
        const int h = hp * HPB + ph;
        if constexpr (MODE <= 1) {
            unsigned* epi = (unsigned*)smem;   // [128][84] packed hi|lo<<16
#pragma unroll
            for (int mt = 0; mt < 2; ++mt)
#pragma unroll
                for (int nt = 0; nt < 5; ++nt)
#pragma unroll
                    for (int r = 0; r < 4; ++r) {
                        u16 hb, lb;
                        split2rne(acc[mt][ph * 5 + nt][r] * scale, hb, lb);  // RNE hi
                        if (patch != 0 && nt == 4 && qc == 11) {             // col d=75
                            if (patch == 1) { hb = (u16)0x3F80; lb = 0; }    // 1.0
                            else {
                                const int sr = s0 + wv * 32 + mt * 16 + g * 4 + r;
                                hb = (pmask[b * SS + sr] != 0) ? (u16)0 : (u16)0xC320; // -160
                                lb = 0;
                            }
                        }
                        epi[(wv * 32 + mt * 16 + g * 4 + r) * 84 + nt * 16 + qc] =
                            (unsigned)hb | ((unsigned)lb << 16);
                    }
            __syncthreads();
            if constexpr (MODE == 0) {
                const int r = t >> 1, half = t & 1;
                const unsigned* row = epi + r * 84 + half * 40;
                const size_t base = ((size_t)(b * NH + h) * SS + s0 + r) * DKP + half * 40;
                u16* dh = hiP + base;
#pragma unroll
                for (int i = 0; i < 5; ++i) {
                    u16x8 hv, lv;
#pragma unroll
                    for (int j = 0; j < 8; ++j) {
                        const unsigned u = row[i * 8 + j];
                        hv[j] = (u16)u; lv[j] = (u16)(u >> 16);
                    }
                    *(u16x8*)(dh + i * 8) = hv;
                    if (loP) *(u16x8*)(loP + base + i * 8) = lv;
                }
            } else {
#pragma unroll
                for (int i = 0; i < 3; ++i) {
                    const int idx = i * 256 + t;
                    if (idx < 640) {
                        const int d = idx >> 3, sc = (idx & 7) * 16;
                        const size_t base = ((size_t)(b * NH + h) * DKP + d) * SS + s0 + sc;
                        u16* dh = hiP + base;
                        u16x8 h0, h1, l0, l1;
#pragma unroll
                        for (int j = 0; j < 8; ++j) {
                            unsigned u = epi[(sc + j) * 84 + d];
                            h0[j] = (u16)u; l0[j] = (u16)(u >> 16);
                            u = epi[(sc + 8 + j) * 84 + d];
                            h1[j] = (u16)u; l1[j] = (u16)(u >> 16);
                        }
                        *(u16x8*)dh = h0; *(u16x8*)(dh + 8) = h1;
                        if (loP) {
                            *(u16x8*)(loP + base) = l0;
                            *(u16x8*)(loP + base + 8) = l1;
                        }
                    }
                }
            }
        } else {
            float* epf = (float*)smem;         // [128][84] fp32
#pragma unroll
            for (int mt = 0; mt < 2; ++mt)
#pragma unroll
                for (int nt = 0; nt < 5; ++nt)
#pragma unroll
                    for (int r = 0; r < 4; ++r)
                        epf[(wv * 32 + mt * 16 + g * 4 + r) * 84 + nt * 16 + qc] =
                            acc[mt][ph * 5 + nt][r];
            __syncthreads();
            for (int i = 0; i < 38; ++i) {
                const int idx = i * 256 + t;
                if (idx < 128 * DK) {
                    const int r = idx / DK, c = idx - r * DK;
                    foutP[(size_t)(row0 + r) * HID + h * DK + c] = epf[r * 84 + c] + bias[h * DK + c];
                }
            }
        }
        if (ph + 1 < HPB) __syncthreads();   // epi buffer reuse by next pass
    }
}

__global__ __launch_bounds__(256, 3)
void proj3_gemm(const float* __restrict__ Aq, const float* __restrict__ Ak,
                const float* __restrict__ Av, const int* __restrict__ mask,
                const u16* __restrict__ wph, const u16* __restrict__ wpl,
                u16* __restrict__ qh, u16* __restrict__ ql,
                u16* __restrict__ kh, u16* __restrict__ vh)
{
    __shared__ char smem[46080];   // staging 46080 > epi 43008
    const int z = blockIdx.z;
    const float* A = (z == 0) ? Aq : (z == 1) ? Ak : Av;
    const size_t WMAT = (size_t)4 * 80 * 320;
    u16* hiP = (z == 0) ? qh : (z == 1) ? kh : vh;
    u16* loP = (z == 0) ? ql : nullptr;
    const float scale = (z == 0) ? C2 : 1.0f;          // fold score scale into Q
    const int patch = (z == 0) ? 1 : (z == 1) ? 2 : 0; // bias column d=75
    if (z == 2)
        gemm_body<1, 2>(smem, A, nullptr, wph + z * WMAT, wpl + z * WMAT,
                        nullptr, hiP, loP, nullptr, blockIdx.x, blockIdx.y,
                        mask, scale, patch);
    else
        gemm_body<0, 2>(smem, A, nullptr, wph + z * WMAT, wpl + z * WMAT,
                        nullptr, hiP, loP, nullptr, blockIdx.x, blockIdx.y,
                        mask, scale, patch);
}

__global__ __launch_bounds__(256)
void out_gemm(const float* __restrict__ A, const float* __restrict__ W,
              const float* __restrict__ bias, float* __restrict__ out)
{
    __shared__ char smem[43008];
    gemm_body<2, 1>(smem, A, W, nullptr, nullptr, bias, nullptr, nullptr, out,
                    blockIdx.x, blockIdx.y, nullptr, 1.0f, 0);
}

// ---------------------------------------------------------------------------
// Flash attention (round-4 version, kept): widened K swizzle (q&15),
// 3-deep global prefetch with two register sets.
// ---------------------------------------------------------------------------
__global__ __launch_bounds__(256, 2)
void attn_mfma32(const u16* __restrict__ qhi, const u16* __restrict__ qlo,
                 const u16* __restrict__ khi, const u16* __restrict__ vhi,
                 const int* __restrict__ mask, float* __restrict__ xout)
{
    __shared__ u16 KsH[2 * 8192];   // [buf][seq 64][256B rows, swizzled]
    __shared__ u16 VsH[2 * 6144];   // [buf][d 96 (80..95 zero)][128B rows]
    __shared__ u16 Ps[4 * 2048];    // per-wave [q 32][seq 64 = 128B rows]

    const int t = threadIdx.x;
    const int wv = t >> 6;
    const int l = t & 63;
    const int q = l & 31;
    const int hi = l >> 5;

    const int bx = blockIdx.x;
    const int xcd = bx & 7, idx = bx >> 3;
    const int bh = xcd * 4 + (idx & 3);
    const int qt = idx >> 2;
    const int b = bh >> 2;
    const int h = bh & 3;
    const int q0 = qt * 128;

    {
        const int rr = (t >> 4) & 15, o8 = t & 15;
        *(uint2*)(VsH + (80 + rr) * 64 + o8 * 4) = make_uint2(0u, 0u);
        *(uint2*)(VsH + 6144 + (80 + rr) * 64 + o8 * 4) = make_uint2(0u, 0u);
    }

    const size_t planeQK = (size_t)bh * (SS * DKP);
    const int qrow = q0 + wv * 32 + q;
    const int mq = (mask[b * SS + qrow] != 0);
    const u16x8 qm = (u16x8)(u16)(mq ? 0xFFFFu : 0u);  // !mq -> Q=0 -> P uniform

    bf16x8 Qh[5], Ql[5];
    {
        const u16* ph = qhi + planeQK + (size_t)qrow * DKP;
        const u16* pl = qlo + planeQK + (size_t)qrow * DKP;
#pragma unroll
        for (int ch = 0; ch < 5; ++ch) {
            u16x8 ua = *(const u16x8*)(ph + 16 * ch + 8 * hi) & qm;
            u16x8 ub = *(const u16x8*)(pl + 16 * ch + 8 * hi) & qm;
            Qh[ch] = *(bf16x8*)&ua;
            Ql[ch] = *(bf16x8*)&ub;
        }
    }

    const u16* kH = khi + planeQK;
    const u16* vH = vhi + (size_t)bh * (DKP * SS);
    u16* PsW = Ps + wv * 2048;

    int kOff[5], kLds[5], vOff[5], vLds[5];
#pragma unroll
    for (int i = 0; i < 5; ++i) {
        const int gi = t + i * 256;
        const int r = gi / 20, c8 = gi % 20;
        kOff[i] = r * 160 + c8 * 8;
        kLds[i] = r * 256 + ((c8 * 8) ^ ((r & 15) << 4));   // widened swizzle
        const int d = gi >> 4, cv = gi & 15;
        vOff[i] = d * 4096 + cv * 8;
        vLds[i] = d * 128 + ((cv * 8) ^ ((d & 7) << 4));
    }

    uint2 krA[5], vrA[5], krB[5], vrB[5];
#define LOADT(KT, KR, VR) do { _Pragma("unroll") \
    for (int i = 0; i < 5; ++i) { \
        KR[i] = *(const uint2*)((const char*)kH + (size_t)(KT) * 10240 + kOff[i]); \
        VR[i] = *(const uint2*)((const char*)vH + (size_t)(KT) * 128 + vOff[i]); \
    } } while (0)
#define WRITET(BUF, KR, VR) do { _Pragma("unroll") \
    for (int i = 0; i < 5; ++i) { \
        *(uint2*)((char*)(KsH + (BUF) * 8192) + kLds[i]) = KR[i]; \
        *(uint2*)((char*)(VsH + (BUF) * 6144) + vLds[i]) = VR[i]; \
    } } while (0)

    LOADT(0, krA, vrA);
    WRITET(0, krA, vrA);
    LOADT(1, krA, vrA);    // A holds kt=1 (consumed at end of kt=0)
    LOADT(2, krB, vrB);    // B holds kt=2 (consumed at end of kt=1)
    __syncthreads();

    f32x16 O[3];
#pragma unroll
    for (int dt = 0; dt < 3; ++dt) O[dt] = (f32x16){};
    float ll = 0.f;
    const int kswz = (q & 15) << 4;        // K-read swizzle (widened)
    const int pswz = (q & 7) << 4;         // Ps swizzle (128B rows)

    for (int kt = 0; kt < 32; ++kt) {
        const int cur = kt & 1;
        const char* Kc = (const char*)(KsH + cur * 8192);
        const char* Vc = (const char*)(VsH + cur * 6144);

        f32x16 s0 = (f32x16){}, s1 = (f32x16){};
#pragma unroll
        for (int ch = 0; ch < 5; ++ch) {
            const int o0 = (32 * ch + 16 * hi) ^ kswz;
            const int o1 = (32 * ch + 16 * hi) ^ (((32 + q) & 15) << 4);
            const bf16x8 a0 = *(const bf16x8*)(Kc + q * 256 + o0);
            const bf16x8 a1 = *(const bf16x8*)(Kc + (32 + q) * 256 + o1);
            s0 = MFMA32(a0, Qh[ch], s0);
            s0 = MFMA32(a0, Ql[ch], s0);
            s1 = MFMA32(a1, Qh[ch], s1);
            s1 = MFMA32(a1, Ql[ch], s1);
        }

        // ---- softmax numerators: e = exp2(s) directly (scale/mask folded) ----
        float p0 = 0.f, p1 = 0.f, p2 = 0.f, p3 = 0.f;
#pragma unroll
        for (int sb = 0; sb < 2; ++sb) {
            const f32x16 sv = sb ? s1 : s0;
            float e[16];
#pragma unroll
            for (int r = 0; r < 16; r += 4) {
                e[r + 0] = __builtin_amdgcn_exp2f(sv[r + 0]);
                e[r + 1] = __builtin_amdgcn_exp2f(sv[r + 1]);
                e[r + 2] = __builtin_amdgcn_exp2f(sv[r + 2]);
                e[r + 3] = __builtin_amdgcn_exp2f(sv[r + 3]);
                p0 += e[r + 0]; p1 += e[r + 1]; p2 += e[r + 2]; p3 += e[r + 3];
            }
#pragma unroll
            for (int rr = 0; rr < 4; ++rr) {
                uint2 w;
                w.x = pkbf(e[4 * rr + 0], e[4 * rr + 1]);
                w.y = pkbf(e[4 * rr + 2], e[4 * rr + 3]);
                const int o = (sb * 64 + 16 * rr + 8 * hi) ^ pswz;
                *(uint2*)((char*)PsW + q * 128 + o) = w;
            }
        }
        ll += (p0 + p1) + (p2 + p3);

        // ---- PV ----
#pragma unroll
        for (int c = 0; c < 4; ++c) {
            const int po = q * 128 + ((32 * c + 16 * hi) ^ pswz);
            const bf16x8 pA = *(const bf16x8*)((char*)PsW + po);
#pragma unroll
            for (int dt = 0; dt < 3; ++dt) {
                const int drow = 32 * dt + q;
                const int vb = drow * 128 + ((32 * c + 16 * hi) ^ ((drow & 7) << 4));
                const bf16x8 vh8 = *(const bf16x8*)(Vc + vb);
                O[dt] = MFMA32(vh8, pA, O[dt]);
            }
        }

        if (kt < 31) {
            if ((kt & 1) == 0) {
                WRITET(cur ^ 1, krA, vrA);
                if (kt < 29) LOADT(kt + 3, krA, vrA);
            } else {
                WRITET(cur ^ 1, krB, vrB);
                if (kt < 29) LOADT(kt + 3, krB, vrB);
            }
        }
        __syncthreads();
    }
#undef LOADT
#undef WRITET

    ll += __shfl_xor(ll, 32);
    {
        const float inv = 1.0f / ll;
        float* o = xout + (size_t)(b * SS + qrow) * HID + h * DK;
#pragma unroll
        for (int dt = 0; dt < 3; ++dt)
#pragma unroll
            for (int r = 0; r < 16; ++r) {
                const int d = 32 * dt + (r & 3) + 8 * (r >> 2) + 4 * hi;
                if (d < DK) o[d] = O[dt][r] * inv;
            }
    }
}

// ---------------------------------------------------------------------------
extern "C" void kernel_launch(void* const* d_in, const int* in_sizes, int n_in,
                              void* d_out, int out_size, void* d_ws, size_t ws_size,
                              hipStream_t stream)
{
    const float* query = (const float*)d_in[0];
    const float* key_t = (const float*)d_in[1];
    const float* value = (const float*)d_in[2];
    const int*   mask  = (const int*)d_in[3];
    const float* Wq    = (const float*)d_in[4];
    const float* Wk    = (const float*)d_in[5];
    const float* Wv    = (const float*)d_in[6];
    const float* Wo    = (const float*)d_in[7];
    const float* bo    = (const float*)d_in[8];
    float* out = (float*)d_out;

    // Proven workspace layout (<=82.58 MB). kl/vl slots retained but unused.
    const size_t PL = (size_t)BB * NH * SS * DKP;
    u16* qh = (u16*)d_ws;
    u16* ql = qh + PL;
    u16* kh = ql + PL;
    u16* kl = kh + PL;   (void)kl;
    u16* vh = kl + PL;
    u16* vl = vh + PL;
    float* xws = (float*)(vl + PL);
    u16* wph = (u16*)xws;                         // [3][4][80][320] hi
    u16* wpl = wph + (size_t)3 * 4 * 80 * 320;    // lo (1.23 MB total)

    const dim3 blk(256, 1, 1);

    prep_w3<<<150, blk, 0, stream>>>(Wq, Wk, Wv, wph, wpl);

    proj3_gemm<<<dim3(128, 2, 3), blk, 0, stream>>>(query, key_t, value, mask,
                                                    wph, wpl,
                                                    qh, ql, kh, vh);

    attn_mfma32<<<dim3(512, 1, 1), blk, 0, stream>>>(qh, ql, kh, vh, mask, xws);

    out_gemm<<<dim3(128, NH, 1), blk, 0, stream>>>(xws, Wo, bo, out);
}